// Round 3
// baseline (308.823 us; speedup 1.0000x reference)
//
#include <hip/hip_runtime.h>
#include <hip/hip_bf16.h>

typedef _Float16 f16;
typedef _Float16 f16x2 __attribute__((ext_vector_type(2)));
typedef _Float16 f16x4 __attribute__((ext_vector_type(4)));
typedef _Float16 f16x8 __attribute__((ext_vector_type(8)));
typedef float f32x4 __attribute__((ext_vector_type(4)));

#define T_TOK 4096
#define V_N 32
#define H_N 256
#define LN_EPS_F 1e-5f

union U4 { f16x4 h; int i[2]; };
union U8 { f16x8 h; int i[4]; };

// ---------------- prep: W2,Wg [v][k][n] f32 -> [v][n][k] f16 ----------------
__global__ __launch_bounds__(256) void prep_transpose(
    const float* __restrict__ W2, const float* __restrict__ Wg,
    f16* __restrict__ W2t, f16* __restrict__ Wgt)
{
    __shared__ float tile[64][65];
    int bid = blockIdx.x;
    int w = bid >> 9;
    int rem = bid & 511;
    int v = rem >> 4;
    int kt = (rem >> 2) & 3;
    int nt = rem & 3;
    const float* src = w ? Wg : W2;
    f16* dst = w ? Wgt : W2t;
    const float* base = src + ((size_t)v * H_N + (size_t)kt * 64) * H_N + nt * 64;
    int tid = threadIdx.x;
    #pragma unroll
    for (int p = 0; p < 16; ++p) {
        int idx = p * 256 + tid;
        int r = idx >> 6, c = idx & 63;
        tile[r][c] = base[(size_t)r * H_N + c];
    }
    __syncthreads();
    f16* obase = dst + ((size_t)v * H_N + (size_t)nt * 64) * H_N + kt * 64;
    #pragma unroll
    for (int p = 0; p < 16; ++p) {
        int idx = p * 256 + tid;
        int r = idx >> 6, c = idx & 63;
        obase[(size_t)r * H_N + c] = (f16)tile[c][r];
    }
}

// ---------------- prep: W1,b1 f32 -> f16 ----------------
__global__ __launch_bounds__(256) void prep_w1(
    const float* __restrict__ W1, const float* __restrict__ b1,
    f16* __restrict__ W1h, f16* __restrict__ b1h)
{
    int i = blockIdx.x * 256 + threadIdx.x;   // grid 32 -> 8192
    W1h[i] = (f16)W1[i];
    b1h[i] = (f16)b1[i];
}

// ---------------- fused GRN, swapped-operand, LDS-free, barrier-free ----------------
// grid 2048 = (v, mt), 256 thr = 4 independent waves; each lane owns ONE token row.
// MFMA convention (verified r1/r2): mfma(af, bf, c) -> D[i][j], i = af-idx (row =
// (lane>>4)*4+reg), j = bf-idx (col = lane&15); both frags are [idx][k = hi*8+e].
__global__ __launch_bounds__(256) void fused_grn(
    const float* __restrict__ x,    // [T][V]
    const f16* __restrict__ W1h, const f16* __restrict__ b1h,   // [V][256]
    const f16* __restrict__ W2t, const float* __restrict__ b2,  // [V][n][k], [V][256]
    const f16* __restrict__ Wgt, const float* __restrict__ bg,
    const float* __restrict__ gamma, const float* __restrict__ beta,
    const float* __restrict__ Wa, const float* __restrict__ ba,
    f16* __restrict__ VO,           // [V][T][H]
    float* __restrict__ scores)     // [T][V]
{
    int bid = blockIdx.x;
    int xcd = bid & 7, rr = bid >> 3;
    int v  = (xcd << 2) + (rr >> 6);     // 4 variables per XCD -> weights L2-local
    int mt = rr & 63;
    int tid = threadIdx.x;
    int w = tid >> 6, lane = tid & 63;
    int lo = lane & 15, hi = lane >> 4;
    int m = mt * 64 + w * 16 + lo;       // token row owned by this lane

    const f16* W2v = W2t + ((size_t)v << 16);
    const f16* Wgv = Wgt + ((size_t)v << 16);

    float xs = x[(size_t)m * V_N + v];
    f16 xh = (f16)xs;
    f16x8 x8 = { xh, xh, xh, xh, xh, xh, xh, xh };

    f32x4 acc[16] = {};   // acc[nf][r]: this lane's H2[m][n], n = nf*16 + hi*4 + r

    // ---- GEMM1: H2 = relu(x*W1+b1) @ W2 ; B-frag (h1^T) generated in-register ----
    #pragma unroll
    for (int kt = 0; kt < 8; ++kt) {
        const int k0 = kt * 32 + hi * 8;
        f16x8 w8 = *(const f16x8*)&W1h[v * H_N + k0];
        f16x8 c8 = *(const f16x8*)&b1h[v * H_N + k0];
        f16x8 hv = x8 * w8 + c8;
        #pragma unroll
        for (int j = 0; j < 8; ++j) hv[j] = hv[j] > (f16)0 ? hv[j] : (f16)0;
        #pragma unroll
        for (int nf = 0; nf < 16; ++nf) {
            f16x8 af = *(const f16x8*)&W2v[(size_t)((nf * 16 + lo) << 8) + k0];
            acc[nf] = __builtin_amdgcn_mfma_f32_16x16x32_f16(af, hv, acc[nf], 0, 0, 0);
        }
    }

    // ---- H2 += b2, pack to f16 pairs (kept in registers) ----
    int H2p[16][2];
    #pragma unroll
    for (int nf = 0; nf < 16; ++nf) {
        f32x4 b4 = *(const f32x4*)&b2[v * H_N + nf * 16 + hi * 4];
        f32x4 h = acc[nf] + b4;
        U4 u; u.h = f16x4{ (f16)h[0], (f16)h[1], (f16)h[2], (f16)h[3] };
        H2p[nf][0] = u.i[0]; H2p[nf][1] = u.i[1];
        acc[nf] = f32x4{0.f, 0.f, 0.f, 0.f};
    }

    // ---- GEMM2: acc = H2 @ Wg ; B-frag built by cross-hi register exchange ----
    // lane (lo,hi) needs H2[m(lo)][k = kt*32 + hi*8 + j]:
    //   nf_src = kt*2 + (hi>>1); src lane = lo + ((2*hi + (j>>2))&3)*16; reg = j&3.
    int iq0 = lo + ((((hi << 1))     & 3) << 4);
    int iq1 = lo + ((((hi << 1) | 1) & 3) << 4);
    bool hiB = (hi >> 1) != 0;
    #pragma unroll
    for (int kt = 0; kt < 8; ++kt) {
        int A0 = H2p[2 * kt][0],     A1 = H2p[2 * kt][1];
        int B0 = H2p[2 * kt + 1][0], B1 = H2p[2 * kt + 1][1];
        int a0 = __shfl(A0, iq0), a1 = __shfl(A1, iq0);
        int a2 = __shfl(A0, iq1), a3 = __shfl(A1, iq1);
        int b0 = __shfl(B0, iq0), b1_ = __shfl(B1, iq0);
        int b2_ = __shfl(B0, iq1), b3 = __shfl(B1, iq1);
        U8 u;
        u.i[0] = hiB ? b0  : a0;
        u.i[1] = hiB ? b1_ : a1;
        u.i[2] = hiB ? b2_ : a2;
        u.i[3] = hiB ? b3  : a3;
        const int k0 = kt * 32 + hi * 8;
        #pragma unroll
        for (int nf = 0; nf < 16; ++nf) {
            f16x8 af = *(const f16x8*)&Wgv[(size_t)((nf * 16 + lo) << 8) + k0];
            acc[nf] = __builtin_amdgcn_mfma_f32_16x16x32_f16(af, u.h, acc[nf], 0, 0, 0);
        }
    }

    // ---- gating (in-register) + LN stats ----
    float s = 0.f, q = 0.f;
    #pragma unroll
    for (int nf = 0; nf < 16; ++nf) {
        f32x4 bgv = *(const f32x4*)&bg[v * H_N + nf * 16 + hi * 4];
        U4 u; u.i[0] = H2p[nf][0]; u.i[1] = H2p[nf][1];
        #pragma unroll
        for (int r = 0; r < 4; ++r) {
            float a = acc[nf][r] + bgv[r];
            float g = 1.f / (1.f + __expf(-a));
            float val = g * (float)u.h[r];
            acc[nf][r] = val;
            s += val; q += val * val;
        }
    }
    // reduce over the 4 stride-16 lanes sharing this row (x residual cancels in LN)
    s += __shfl_xor(s, 16); s += __shfl_xor(s, 32);
    q += __shfl_xor(q, 16); q += __shfl_xor(q, 32);
    float mu  = s * (1.f / 256.f);
    float var = q * (1.f / 256.f) - mu * mu;
    float inv = rsqrtf(var + LN_EPS_F);

    // ---- normalize + score + VO write ----
    float sp = 0.f;
    f16* VOr = VO + ((size_t)v * T_TOK + m) * H_N;
    #pragma unroll
    for (int nf = 0; nf < 16; ++nf) {
        int n0 = nf * 16 + hi * 4;
        f32x4 gm = *(const f32x4*)&gamma[v * H_N + n0];
        f32x4 bt = *(const f32x4*)&beta[v * H_N + n0];
        f32x4 wa = *(const f32x4*)&Wa[n0];
        f16x4 ov;
        #pragma unroll
        for (int r = 0; r < 4; ++r) {
            float o = (acc[nf][r] - mu) * inv * gm[r] + bt[r];
            sp += o * wa[r];
            ov[r] = (f16)o;
        }
        *(f16x4*)&VOr[n0] = ov;
    }
    sp += __shfl_xor(sp, 16); sp += __shfl_xor(sp, 32);
    if (hi == 0) scores[(size_t)m * V_N + v] = sp + ba[0];
}

// ---------------- softmax over V + pooled sum ----------------
__global__ __launch_bounds__(128) void pool(
    const f16* __restrict__ VO,       // [V][T][H]
    const float* __restrict__ scores, // [T][V]
    float* __restrict__ out)          // [T*H] vsn, then [T*V] attn
{
    int t = blockIdx.x, tid = threadIdx.x;
    __shared__ float sc[V_N];
    if (tid < V_N) sc[tid] = scores[t * V_N + tid];
    __syncthreads();
    float mx = -1e30f;
    #pragma unroll
    for (int v = 0; v < V_N; ++v) mx = fmaxf(mx, sc[v]);
    float e[V_N];
    float sum = 0.f;
    #pragma unroll
    for (int v = 0; v < V_N; ++v) { e[v] = __expf(sc[v] - mx); sum += e[v]; }
    float isum = 1.f / sum;
    float a0 = 0.f, a1 = 0.f;
    #pragma unroll
    for (int v = 0; v < V_N; ++v) {
        f16x2 vv = *(const f16x2*)&VO[((size_t)v * T_TOK + t) * H_N + tid * 2];
        float ww = e[v] * isum;
        a0 = fmaf((float)vv[0], ww, a0);
        a1 = fmaf((float)vv[1], ww, a1);
    }
    *(float2*)&out[(size_t)t * H_N + tid * 2] = make_float2(a0, a1);
    if (tid < V_N)
        out[(size_t)T_TOK * H_N + (size_t)t * V_N + tid] = e[tid] * isum;
}

extern "C" void kernel_launch(void* const* d_in, const int* in_sizes, int n_in,
                              void* d_out, int out_size, void* d_ws, size_t ws_size,
                              hipStream_t stream)
{
    const float* x     = (const float*)d_in[0];
    const float* W1    = (const float*)d_in[1];
    const float* b1    = (const float*)d_in[2];
    const float* W2    = (const float*)d_in[3];
    const float* b2    = (const float*)d_in[4];
    const float* Wg    = (const float*)d_in[5];
    const float* bg    = (const float*)d_in[6];
    const float* gamma = (const float*)d_in[7];
    const float* beta  = (const float*)d_in[8];
    const float* Wa    = (const float*)d_in[9];
    const float* ba    = (const float*)d_in[10];
    float* out = (float*)d_out;

    char* ws = (char*)d_ws;
    f16* W2t = (f16*)ws;                                        // 4 MB
    f16* Wgt = (f16*)(ws + ((size_t)4 << 20));                  // 4 MB
    f16* VO  = (f16*)(ws + ((size_t)8 << 20));                  // 64 MB
    float* scores = (float*)(ws + ((size_t)72 << 20));          // 512 KB
    f16* W1h = (f16*)(ws + ((size_t)72 << 20) + (512 << 10));   // 16 KB
    f16* b1h = (f16*)(ws + ((size_t)72 << 20) + (528 << 10));   // 16 KB

    prep_transpose<<<1024, 256, 0, stream>>>(W2, Wg, W2t, Wgt);
    prep_w1<<<32, 256, 0, stream>>>(W1, b1, W1h, b1h);
    fused_grn<<<2048, 256, 0, stream>>>(x, W1h, b1h, W2t, b2, Wgt, bg,
                                        gamma, beta, Wa, ba, VO, scores);
    pool<<<4096, 128, 0, stream>>>(VO, scores, out);
}

// Round 4
// 152.244 us; speedup vs baseline: 2.0285x; 2.0285x over previous
//
#include <hip/hip_runtime.h>
#include <hip/hip_bf16.h>

typedef _Float16 f16;
typedef _Float16 f16x2 __attribute__((ext_vector_type(2)));
typedef _Float16 f16x4 __attribute__((ext_vector_type(4)));
typedef _Float16 f16x8 __attribute__((ext_vector_type(8)));
typedef float f32x4 __attribute__((ext_vector_type(4)));

#define T_TOK 4096
#define V_N 32
#define H_N 256
#define LN_EPS_F 1e-5f

union U4 { f16x4 h; int i[2]; };
union U8 { f16x8 h; int i[4]; };

__device__ __forceinline__ void gload16(const f16* g, f16* l) {
    __builtin_amdgcn_global_load_lds(
        (const __attribute__((address_space(1))) void*)g,
        (__attribute__((address_space(3))) void*)l, 16, 0, 0);
}

// ---------------- prep: W2,Wg [v][k][n] f32 -> [v][n][k] f16 ----------------
__global__ __launch_bounds__(256) void prep_transpose(
    const float* __restrict__ W2, const float* __restrict__ Wg,
    f16* __restrict__ W2t, f16* __restrict__ Wgt)
{
    __shared__ float tile[64][65];
    int bid = blockIdx.x;
    int w = bid >> 9;
    int rem = bid & 511;
    int v = rem >> 4;
    int kt = (rem >> 2) & 3;
    int nt = rem & 3;
    const float* src = w ? Wg : W2;
    f16* dst = w ? Wgt : W2t;
    const float* base = src + ((size_t)v * H_N + (size_t)kt * 64) * H_N + nt * 64;
    int tid = threadIdx.x;
    #pragma unroll
    for (int p = 0; p < 16; ++p) {
        int idx = p * 256 + tid;
        int r = idx >> 6, c = idx & 63;
        tile[r][c] = base[(size_t)r * H_N + c];
    }
    __syncthreads();
    f16* obase = dst + ((size_t)v * H_N + (size_t)nt * 64) * H_N + kt * 64;
    #pragma unroll
    for (int p = 0; p < 16; ++p) {
        int idx = p * 256 + tid;
        int r = idx >> 6, c = idx & 63;
        obase[(size_t)r * H_N + c] = (f16)tile[c][r];
    }
}

// ---------------- prep: W1,b1 f32 -> f16 ----------------
__global__ __launch_bounds__(256) void prep_w1(
    const float* __restrict__ W1, const float* __restrict__ b1,
    f16* __restrict__ W1h, f16* __restrict__ b1h)
{
    int i = blockIdx.x * 256 + threadIdx.x;   // grid 32 -> 8192
    W1h[i] = (f16)W1[i];
    b1h[i] = (f16)b1[i];
}

// ---------------- fused GRN: swapped-operand, LDS-staged weights ----------------
// grid 1024 = (v, mt), 256 thr = 4 waves; wave owns 32 tokens (2 groups of 16).
// Weights staged per-32k-slice into LDS (double buffer), chunk-XOR swizzled at the
// global source (linear LDS dest), read back swizzled as ds_read_b128 fragments.
__global__ __launch_bounds__(256, 2) void fused_grn(
    const float* __restrict__ x,    // [T][V]
    const f16* __restrict__ W1h, const f16* __restrict__ b1h,   // [V][256]
    const f16* __restrict__ W2t, const float* __restrict__ b2,  // [V][n][k]
    const f16* __restrict__ Wgt, const float* __restrict__ bg,
    const float* __restrict__ gamma, const float* __restrict__ beta,
    const float* __restrict__ Wa, const float* __restrict__ ba,
    f16* __restrict__ VO,           // [V][T][H]
    float* __restrict__ scores)     // [T][V]
{
    __shared__ f16 Wb[2][256 * 32];  // two 16KB k-slices (n=256, k=32)

    int bid = blockIdx.x;
    int xcd = bid & 7, rr = bid >> 3;
    int v  = (xcd << 2) + (rr >> 5);   // 4 variables per XCD -> weights L2-local
    int mt = rr & 31;
    int tid = threadIdx.x;
    int w = tid >> 6, lane = tid & 63;
    int lo = lane & 15, hi = lane >> 4;
    int m0 = mt * 128 + w * 32;        // wave's tokens: m0 + g*16 + lo

    const f16* W2v = W2t + ((size_t)v << 16);
    const f16* Wgv = Wgt + ((size_t)v << 16);

    // stage k-slice kt of Wv into Wb[buf]; dest linear (wave base + lane*16B),
    // source chunk XOR-swizzled: LDS (row n, chunk c) holds global chunk c^(n&3)
    auto stage = [&](const f16* Wv, int kt, int buf) {
        #pragma unroll
        for (int i = 0; i < 4; ++i) {
            int n  = ((w * 4 + i) << 4) + (lane >> 2);
            int cs = (lane & 3) ^ (n & 3);
            gload16(Wv + ((size_t)n << 8) + (kt << 5) + (cs << 3),
                    &Wb[buf][(w * 4 + i) << 9]);
        }
    };

    float xs0 = x[(size_t)(m0 + lo) * V_N + v];
    float xs1 = x[(size_t)(m0 + 16 + lo) * V_N + v];
    f16 xh0 = (f16)xs0, xh1 = (f16)xs1;
    f16x8 x80 = { xh0, xh0, xh0, xh0, xh0, xh0, xh0, xh0 };
    f16x8 x81 = { xh1, xh1, xh1, xh1, xh1, xh1, xh1, xh1 };

    f32x4 acc0[16] = {}, acc1[16] = {};
    const int afbase = ((hi ^ (lo & 3)) << 3);   // swizzled k-chunk within row

    stage(W2v, 0, 0);
    __syncthreads();

    // ---- GEMM1: H2 = relu(x*W1+b1) @ W2 ----
    #pragma unroll
    for (int kt = 0; kt < 8; ++kt) {
        if (kt < 7) stage(W2v, kt + 1, (kt + 1) & 1);
        else        stage(Wgv, 0, 0);          // prefetch GEMM2 slice 0
        const int k0 = (kt << 5) + (hi << 3);
        f16x8 w8 = *(const f16x8*)&W1h[(v << 8) + k0];
        f16x8 c8 = *(const f16x8*)&b1h[(v << 8) + k0];
        f16x8 hv0 = x80 * w8 + c8;
        f16x8 hv1 = x81 * w8 + c8;
        #pragma unroll
        for (int j = 0; j < 8; ++j) {
            hv0[j] = hv0[j] > (f16)0 ? hv0[j] : (f16)0;
            hv1[j] = hv1[j] > (f16)0 ? hv1[j] : (f16)0;
        }
        #pragma unroll
        for (int nf = 0; nf < 16; ++nf) {
            f16x8 af = *(const f16x8*)&Wb[kt & 1][((nf * 16 + lo) << 5) + afbase];
            acc0[nf] = __builtin_amdgcn_mfma_f32_16x16x32_f16(af, hv0, acc0[nf], 0, 0, 0);
            acc1[nf] = __builtin_amdgcn_mfma_f32_16x16x32_f16(af, hv1, acc1[nf], 0, 0, 0);
        }
        __syncthreads();
    }

    // ---- H2 += b2, pack to f16 (registers); re-zero acc ----
    int H2p0[16][2], H2p1[16][2];
    #pragma unroll
    for (int nf = 0; nf < 16; ++nf) {
        f32x4 b4 = *(const f32x4*)&b2[(v << 8) + nf * 16 + hi * 4];
        f32x4 h0 = acc0[nf] + b4;
        f32x4 h1 = acc1[nf] + b4;
        U4 u0; u0.h = f16x4{ (f16)h0[0], (f16)h0[1], (f16)h0[2], (f16)h0[3] };
        U4 u1; u1.h = f16x4{ (f16)h1[0], (f16)h1[1], (f16)h1[2], (f16)h1[3] };
        H2p0[nf][0] = u0.i[0]; H2p0[nf][1] = u0.i[1];
        H2p1[nf][0] = u1.i[0]; H2p1[nf][1] = u1.i[1];
        acc0[nf] = f32x4{0.f, 0.f, 0.f, 0.f};
        acc1[nf] = f32x4{0.f, 0.f, 0.f, 0.f};
    }

    // ---- GEMM2: acc = H2 @ Wg ; B-frag via cross-hi register exchange ----
    // (verified r3): nf_src = kt*2 + (hi>>1); src lane = lo + ((2hi+q)&3)*16; reg = q&...
    int iq0 = lo + ((((hi << 1))     & 3) << 4);
    int iq1 = lo + ((((hi << 1) | 1) & 3) << 4);
    bool hiB = (hi >> 1) != 0;
    #pragma unroll
    for (int kt = 0; kt < 8; ++kt) {
        if (kt < 7) stage(Wgv, kt + 1, (kt + 1) & 1);
        U8 u0, u1;
        {
            int A0 = H2p0[2 * kt][0],     A1 = H2p0[2 * kt][1];
            int B0 = H2p0[2 * kt + 1][0], B1 = H2p0[2 * kt + 1][1];
            int a0 = __shfl(A0, iq0), a1 = __shfl(A1, iq0);
            int a2 = __shfl(A0, iq1), a3 = __shfl(A1, iq1);
            int b0 = __shfl(B0, iq0), b1_ = __shfl(B1, iq0);
            int b2_ = __shfl(B0, iq1), b3 = __shfl(B1, iq1);
            u0.i[0] = hiB ? b0  : a0;
            u0.i[1] = hiB ? b1_ : a1;
            u0.i[2] = hiB ? b2_ : a2;
            u0.i[3] = hiB ? b3  : a3;
        }
        {
            int A0 = H2p1[2 * kt][0],     A1 = H2p1[2 * kt][1];
            int B0 = H2p1[2 * kt + 1][0], B1 = H2p1[2 * kt + 1][1];
            int a0 = __shfl(A0, iq0), a1 = __shfl(A1, iq0);
            int a2 = __shfl(A0, iq1), a3 = __shfl(A1, iq1);
            int b0 = __shfl(B0, iq0), b1_ = __shfl(B1, iq0);
            int b2_ = __shfl(B0, iq1), b3 = __shfl(B1, iq1);
            u1.i[0] = hiB ? b0  : a0;
            u1.i[1] = hiB ? b1_ : a1;
            u1.i[2] = hiB ? b2_ : a2;
            u1.i[3] = hiB ? b3  : a3;
        }
        #pragma unroll
        for (int nf = 0; nf < 16; ++nf) {
            f16x8 af = *(const f16x8*)&Wb[kt & 1][((nf * 16 + lo) << 5) + afbase];
            acc0[nf] = __builtin_amdgcn_mfma_f32_16x16x32_f16(af, u0.h, acc0[nf], 0, 0, 0);
            acc1[nf] = __builtin_amdgcn_mfma_f32_16x16x32_f16(af, u1.h, acc1[nf], 0, 0, 0);
        }
        if (kt < 7) __syncthreads();
    }

    // ---- gating + LN + score + VO, per token group, all in registers ----
    #pragma unroll
    for (int g = 0; g < 2; ++g) {
        f32x4* acc = g ? acc1 : acc0;
        int (*H2p)[2] = g ? H2p1 : H2p0;
        int m = m0 + g * 16 + lo;
        float s = 0.f, q = 0.f;
        #pragma unroll
        for (int nf = 0; nf < 16; ++nf) {
            f32x4 bgv = *(const f32x4*)&bg[(v << 8) + nf * 16 + hi * 4];
            U4 u; u.i[0] = H2p[nf][0]; u.i[1] = H2p[nf][1];
            #pragma unroll
            for (int r = 0; r < 4; ++r) {
                float a = acc[nf][r] + bgv[r];
                float gg = 1.f / (1.f + __expf(-a));
                float val = gg * (float)u.h[r];
                acc[nf][r] = val;
                s += val; q += val * val;
            }
        }
        s += __shfl_xor(s, 16); s += __shfl_xor(s, 32);
        q += __shfl_xor(q, 16); q += __shfl_xor(q, 32);
        float mu  = s * (1.f / 256.f);
        float var = q * (1.f / 256.f) - mu * mu;
        float inv = rsqrtf(var + LN_EPS_F);
        float sp = 0.f;
        f16* VOr = VO + ((size_t)v * T_TOK + m) * H_N;
        #pragma unroll
        for (int nf = 0; nf < 16; ++nf) {
            int n0 = nf * 16 + hi * 4;
            f32x4 gm = *(const f32x4*)&gamma[(v << 8) + n0];
            f32x4 bt = *(const f32x4*)&beta[(v << 8) + n0];
            f32x4 wa = *(const f32x4*)&Wa[n0];
            f16x4 ov;
            #pragma unroll
            for (int r = 0; r < 4; ++r) {
                float o = (acc[nf][r] - mu) * inv * gm[r] + bt[r];
                sp += o * wa[r];
                ov[r] = (f16)o;
            }
            *(f16x4*)&VOr[n0] = ov;
        }
        sp += __shfl_xor(sp, 16); sp += __shfl_xor(sp, 32);
        if (hi == 0) scores[(size_t)m * V_N + v] = sp + ba[0];
    }
}

// ---------------- softmax over V + pooled sum ----------------
__global__ __launch_bounds__(128) void pool(
    const f16* __restrict__ VO,       // [V][T][H]
    const float* __restrict__ scores, // [T][V]
    float* __restrict__ out)          // [T*H] vsn, then [T*V] attn
{
    int t = blockIdx.x, tid = threadIdx.x;
    __shared__ float sc[V_N];
    if (tid < V_N) sc[tid] = scores[t * V_N + tid];
    __syncthreads();
    float mx = -1e30f;
    #pragma unroll
    for (int v = 0; v < V_N; ++v) mx = fmaxf(mx, sc[v]);
    float e[V_N];
    float sum = 0.f;
    #pragma unroll
    for (int v = 0; v < V_N; ++v) { e[v] = __expf(sc[v] - mx); sum += e[v]; }
    float isum = 1.f / sum;
    float a0 = 0.f, a1 = 0.f;
    #pragma unroll
    for (int v = 0; v < V_N; ++v) {
        f16x2 vv = *(const f16x2*)&VO[((size_t)v * T_TOK + t) * H_N + tid * 2];
        float ww = e[v] * isum;
        a0 = fmaf((float)vv[0], ww, a0);
        a1 = fmaf((float)vv[1], ww, a1);
    }
    *(float2*)&out[(size_t)t * H_N + tid * 2] = make_float2(a0, a1);
    if (tid < V_N)
        out[(size_t)T_TOK * H_N + (size_t)t * V_N + tid] = e[tid] * isum;
}

extern "C" void kernel_launch(void* const* d_in, const int* in_sizes, int n_in,
                              void* d_out, int out_size, void* d_ws, size_t ws_size,
                              hipStream_t stream)
{
    const float* x     = (const float*)d_in[0];
    const float* W1    = (const float*)d_in[1];
    const float* b1    = (const float*)d_in[2];
    const float* W2    = (const float*)d_in[3];
    const float* b2    = (const float*)d_in[4];
    const float* Wg    = (const float*)d_in[5];
    const float* bg    = (const float*)d_in[6];
    const float* gamma = (const float*)d_in[7];
    const float* beta  = (const float*)d_in[8];
    const float* Wa    = (const float*)d_in[9];
    const float* ba    = (const float*)d_in[10];
    float* out = (float*)d_out;

    char* ws = (char*)d_ws;
    f16* W2t = (f16*)ws;                                        // 4 MB
    f16* Wgt = (f16*)(ws + ((size_t)4 << 20));                  // 4 MB
    f16* VO  = (f16*)(ws + ((size_t)8 << 20));                  // 64 MB
    float* scores = (float*)(ws + ((size_t)72 << 20));          // 512 KB
    f16* W1h = (f16*)(ws + ((size_t)72 << 20) + (512 << 10));   // 16 KB
    f16* b1h = (f16*)(ws + ((size_t)72 << 20) + (528 << 10));   // 16 KB

    prep_transpose<<<1024, 256, 0, stream>>>(W2, Wg, W2t, Wgt);
    prep_w1<<<32, 256, 0, stream>>>(W1, b1, W1h, b1h);
    fused_grn<<<1024, 256, 0, stream>>>(x, W1h, b1h, W2t, b2, Wgt, bg,
                                        gamma, beta, Wa, ba, VO, scores);
    pool<<<4096, 128, 0, stream>>>(VO, scores, out);
}

// Round 5
// 120.871 us; speedup vs baseline: 2.5550x; 1.2596x over previous
//
#include <hip/hip_runtime.h>
#include <hip/hip_bf16.h>

typedef _Float16 f16;
typedef _Float16 f16x2 __attribute__((ext_vector_type(2)));
typedef _Float16 f16x4 __attribute__((ext_vector_type(4)));
typedef _Float16 f16x8 __attribute__((ext_vector_type(8)));
typedef float f32x4 __attribute__((ext_vector_type(4)));

#define T_TOK 4096
#define V_N 32
#define H_N 256
#define LN_EPS_F 1e-5f

union U4 { f16x4 h; int i[2]; };
union U8 { f16x8 h; int i[4]; };

__device__ __forceinline__ void gload16(const f16* g, f16* l) {
    __builtin_amdgcn_global_load_lds(
        (const __attribute__((address_space(1))) void*)g,
        (__attribute__((address_space(3))) void*)l, 16, 0, 0);
}

// ---------------- prep: W2,Wg [v][k][n] f32 -> [v][n][k] f16 ----------------
__global__ __launch_bounds__(256) void prep_transpose(
    const float* __restrict__ W2, const float* __restrict__ Wg,
    f16* __restrict__ W2t, f16* __restrict__ Wgt)
{
    __shared__ float tile[64][65];
    int bid = blockIdx.x;
    int w = bid >> 9;
    int rem = bid & 511;
    int v = rem >> 4;
    int kt = (rem >> 2) & 3;
    int nt = rem & 3;
    const float* src = w ? Wg : W2;
    f16* dst = w ? Wgt : W2t;
    const float* base = src + ((size_t)v * H_N + (size_t)kt * 64) * H_N + nt * 64;
    int tid = threadIdx.x;
    #pragma unroll
    for (int p = 0; p < 16; ++p) {
        int idx = p * 256 + tid;
        int r = idx >> 6, c = idx & 63;
        tile[r][c] = base[(size_t)r * H_N + c];
    }
    __syncthreads();
    f16* obase = dst + ((size_t)v * H_N + (size_t)nt * 64) * H_N + kt * 64;
    #pragma unroll
    for (int p = 0; p < 16; ++p) {
        int idx = p * 256 + tid;
        int r = idx >> 6, c = idx & 63;
        obase[(size_t)r * H_N + c] = (f16)tile[c][r];
    }
}

// ---------------- prep: W1,b1 f32 -> f16 ----------------
__global__ __launch_bounds__(256) void prep_w1(
    const float* __restrict__ W1, const float* __restrict__ b1,
    f16* __restrict__ W1h, f16* __restrict__ b1h)
{
    int i = blockIdx.x * 256 + threadIdx.x;   // grid 32 -> 8192
    W1h[i] = (f16)W1[i];
    b1h[i] = (f16)b1[i];
}

// ---------------- fused GRN: swapped-operand, LDS-staged weights, G=1 ----------------
// grid 2048 = (v, mt64), 256 thr = 4 waves; each lane owns ONE token row (16/wave).
// Weight k-slices (256n x 32k) double-buffered in LDS via global_load_lds;
// bank-uniform XOR swizzle: slot c of row n holds global chunk c ^ (n&3) ^ ((n>>2)&3).
__global__ __launch_bounds__(256, 2) void fused_grn(
    const float* __restrict__ x,    // [T][V]
    const f16* __restrict__ W1h, const f16* __restrict__ b1h,   // [V][256]
    const f16* __restrict__ W2t, const float* __restrict__ b2,  // [V][n][k]
    const f16* __restrict__ Wgt, const float* __restrict__ bg,
    const float* __restrict__ gamma, const float* __restrict__ beta,
    const float* __restrict__ Wa, const float* __restrict__ ba,
    f16* __restrict__ VO,           // [V][T][H]
    float* __restrict__ scores)     // [T][V]
{
    __shared__ f16 Wb[2][256 * 32];  // two 16KB k-slices

    int bid = blockIdx.x;
    int xcd = bid & 7, rr = bid >> 3;
    int v  = (xcd << 2) + (rr >> 6);   // 4 variables per XCD -> weights L2-local
    int mt = rr & 63;
    int tid = threadIdx.x;
    int w = tid >> 6, lane = tid & 63;
    int lo = lane & 15, hi = lane >> 4;
    int m = mt * 64 + w * 16 + lo;     // this lane's token row

    const f16* W2v = W2t + ((size_t)v << 16);
    const f16* Wgv = Wgt + ((size_t)v << 16);

    // stage k-slice kt into Wb[buf]; linear LDS dest, source chunk pre-swizzled
    auto stage = [&](const f16* Wv, int kt, int buf) {
        int cs = (lane & 3) ^ ((lane >> 2) & 3) ^ ((lane >> 4) & 3);
        #pragma unroll
        for (int i = 0; i < 4; ++i) {
            int n = ((w * 4 + i) << 4) + (lane >> 2);
            gload16(Wv + ((size_t)n << 8) + (kt << 5) + (cs << 3),
                    &Wb[buf][(w * 4 + i) << 9]);
        }
    };

    float xs = x[(size_t)m * V_N + v];
    f16 xh = (f16)xs;
    f16x8 x8 = { xh, xh, xh, xh, xh, xh, xh, xh };

    f32x4 acc[16] = {};
    const int afbase = ((hi ^ (lo & 3) ^ ((lo >> 2) & 3)) << 3);

    stage(W2v, 0, 0);
    __syncthreads();

    // ---- GEMM1: H2 = relu(x*W1+b1) @ W2 ; B-frag generated in-register ----
    #pragma unroll
    for (int kt = 0; kt < 8; ++kt) {
        if (kt < 7) stage(W2v, kt + 1, (kt + 1) & 1);
        else        stage(Wgv, 0, 0);          // prefetch GEMM2 slice 0
        const int k0 = (kt << 5) + (hi << 3);
        f16x8 w8 = *(const f16x8*)&W1h[(v << 8) + k0];
        f16x8 c8 = *(const f16x8*)&b1h[(v << 8) + k0];
        f16x8 hv = x8 * w8 + c8;
        #pragma unroll
        for (int j = 0; j < 8; ++j) hv[j] = hv[j] > (f16)0 ? hv[j] : (f16)0;
        #pragma unroll
        for (int nf = 0; nf < 16; ++nf) {
            f16x8 af = *(const f16x8*)&Wb[kt & 1][((nf * 16 + lo) << 5) + afbase];
            acc[nf] = __builtin_amdgcn_mfma_f32_16x16x32_f16(af, hv, acc[nf], 0, 0, 0);
        }
        __syncthreads();
    }

    // ---- H2 += b2, pack to f16 (registers); re-zero acc ----
    int H2p[16][2];
    #pragma unroll
    for (int nf = 0; nf < 16; ++nf) {
        f32x4 b4 = *(const f32x4*)&b2[(v << 8) + nf * 16 + hi * 4];
        f32x4 h = acc[nf] + b4;
        U4 u; u.h = f16x4{ (f16)h[0], (f16)h[1], (f16)h[2], (f16)h[3] };
        H2p[nf][0] = u.i[0]; H2p[nf][1] = u.i[1];
        acc[nf] = f32x4{0.f, 0.f, 0.f, 0.f};
    }

    // ---- GEMM2: acc = H2 @ Wg ; B-frag via cross-hi register exchange (verified r3) ----
    int iq0 = lo + ((((hi << 1))     & 3) << 4);
    int iq1 = lo + ((((hi << 1) | 1) & 3) << 4);
    bool hiB = (hi >> 1) != 0;
    #pragma unroll
    for (int kt = 0; kt < 8; ++kt) {
        if (kt < 7) stage(Wgv, kt + 1, (kt + 1) & 1);
        int A0 = H2p[2 * kt][0],     A1 = H2p[2 * kt][1];
        int B0 = H2p[2 * kt + 1][0], B1 = H2p[2 * kt + 1][1];
        int a0 = __shfl(A0, iq0), a1 = __shfl(A1, iq0);
        int a2 = __shfl(A0, iq1), a3 = __shfl(A1, iq1);
        int b0 = __shfl(B0, iq0), b1_ = __shfl(B1, iq0);
        int b2_ = __shfl(B0, iq1), b3 = __shfl(B1, iq1);
        U8 u;
        u.i[0] = hiB ? b0  : a0;
        u.i[1] = hiB ? b1_ : a1;
        u.i[2] = hiB ? b2_ : a2;
        u.i[3] = hiB ? b3  : a3;
        #pragma unroll
        for (int nf = 0; nf < 16; ++nf) {
            f16x8 af = *(const f16x8*)&Wb[kt & 1][((nf * 16 + lo) << 5) + afbase];
            acc[nf] = __builtin_amdgcn_mfma_f32_16x16x32_f16(af, u.h, acc[nf], 0, 0, 0);
        }
        if (kt < 7) __syncthreads();
    }

    // ---- gating + LN stats, all in registers ----
    float s = 0.f, q = 0.f;
    #pragma unroll
    for (int nf = 0; nf < 16; ++nf) {
        f32x4 bgv = *(const f32x4*)&bg[(v << 8) + nf * 16 + hi * 4];
        U4 u; u.i[0] = H2p[nf][0]; u.i[1] = H2p[nf][1];
        #pragma unroll
        for (int r = 0; r < 4; ++r) {
            float a = acc[nf][r] + bgv[r];
            float g = 1.f / (1.f + __expf(-a));
            float val = g * (float)u.h[r];
            acc[nf][r] = val;
            s += val; q += val * val;
        }
    }
    s += __shfl_xor(s, 16); s += __shfl_xor(s, 32);
    q += __shfl_xor(q, 16); q += __shfl_xor(q, 32);
    float mu  = s * (1.f / 256.f);
    float var = q * (1.f / 256.f) - mu * mu;
    float inv = rsqrtf(var + LN_EPS_F);

    // ---- normalize + score + VO write ----
    float sp = 0.f;
    f16* VOr = VO + ((size_t)v * T_TOK + m) * H_N;
    #pragma unroll
    for (int nf = 0; nf < 16; ++nf) {
        int n0 = nf * 16 + hi * 4;
        f32x4 gm = *(const f32x4*)&gamma[(v << 8) + n0];
        f32x4 bt = *(const f32x4*)&beta[(v << 8) + n0];
        f32x4 wa = *(const f32x4*)&Wa[n0];
        f16x4 ov;
        #pragma unroll
        for (int r = 0; r < 4; ++r) {
            float o = (acc[nf][r] - mu) * inv * gm[r] + bt[r];
            sp += o * wa[r];
            ov[r] = (f16)o;
        }
        *(f16x4*)&VOr[n0] = ov;
    }
    sp += __shfl_xor(sp, 16); sp += __shfl_xor(sp, 32);
    if (hi == 0) scores[(size_t)m * V_N + v] = sp + ba[0];
}

// ---------------- softmax over V + pooled sum ----------------
__global__ __launch_bounds__(128) void pool(
    const f16* __restrict__ VO,       // [V][T][H]
    const float* __restrict__ scores, // [T][V]
    float* __restrict__ out)          // [T*H] vsn, then [T*V] attn
{
    int t = blockIdx.x, tid = threadIdx.x;
    __shared__ float sc[V_N];
    if (tid < V_N) sc[tid] = scores[t * V_N + tid];
    __syncthreads();
    float mx = -1e30f;
    #pragma unroll
    for (int v = 0; v < V_N; ++v) mx = fmaxf(mx, sc[v]);
    float e[V_N];
    float sum = 0.f;
    #pragma unroll
    for (int v = 0; v < V_N; ++v) { e[v] = __expf(sc[v] - mx); sum += e[v]; }
    float isum = 1.f / sum;
    float a0 = 0.f, a1 = 0.f;
    #pragma unroll
    for (int v = 0; v < V_N; ++v) {
        f16x2 vv = *(const f16x2*)&VO[((size_t)v * T_TOK + t) * H_N + tid * 2];
        float ww = e[v] * isum;
        a0 = fmaf((float)vv[0], ww, a0);
        a1 = fmaf((float)vv[1], ww, a1);
    }
    *(float2*)&out[(size_t)t * H_N + tid * 2] = make_float2(a0, a1);
    if (tid < V_N)
        out[(size_t)T_TOK * H_N + (size_t)t * V_N + tid] = e[tid] * isum;
}

extern "C" void kernel_launch(void* const* d_in, const int* in_sizes, int n_in,
                              void* d_out, int out_size, void* d_ws, size_t ws_size,
                              hipStream_t stream)
{
    const float* x     = (const float*)d_in[0];
    const float* W1    = (const float*)d_in[1];
    const float* b1    = (const float*)d_in[2];
    const float* W2    = (const float*)d_in[3];
    const float* b2    = (const float*)d_in[4];
    const float* Wg    = (const float*)d_in[5];
    const float* bg    = (const float*)d_in[6];
    const float* gamma = (const float*)d_in[7];
    const float* beta  = (const float*)d_in[8];
    const float* Wa    = (const float*)d_in[9];
    const float* ba    = (const float*)d_in[10];
    float* out = (float*)d_out;

    char* ws = (char*)d_ws;
    f16* W2t = (f16*)ws;                                        // 4 MB
    f16* Wgt = (f16*)(ws + ((size_t)4 << 20));                  // 4 MB
    f16* VO  = (f16*)(ws + ((size_t)8 << 20));                  // 64 MB
    float* scores = (float*)(ws + ((size_t)72 << 20));          // 512 KB
    f16* W1h = (f16*)(ws + ((size_t)72 << 20) + (512 << 10));   // 16 KB
    f16* b1h = (f16*)(ws + ((size_t)72 << 20) + (528 << 10));   // 16 KB

    prep_transpose<<<1024, 256, 0, stream>>>(W2, Wg, W2t, Wgt);
    prep_w1<<<32, 256, 0, stream>>>(W1, b1, W1h, b1h);
    fused_grn<<<2048, 256, 0, stream>>>(x, W1h, b1h, W2t, b2, Wgt, bg,
                                        gamma, beta, Wa, ba, VO, scores);
    pool<<<4096, 128, 0, stream>>>(VO, scores, out);
}